// Round 7
// baseline (212.997 us; speedup 1.0000x reference)
//
#include <hip/hip_runtime.h>
#include <hip/hip_bf16.h>

// DendriticLayerSiLU: out = silu(softmax-gated template proj) * (x @ W^T)
// N=4096 tokens, K=2048, H=1024, 32 windows of 64.
// Round 7: work-volume reduction. X global->VGPR (no LDS), LDS = W/T only,
// wave tile 64x32 (LDS reads /3.3), exp2-based EPILOG with log2e folded
// into the T prepass (VALU /1.7). Sync structure = validated r4 2-phase.

typedef __attribute__((ext_vector_type(8))) short short8;
typedef __attribute__((ext_vector_type(4))) float f32x4;

#define N_TOK 4096
#define K_DIM 2048
#define H_DIM 1024
#define BM 128
#define BH 128
#define BK 32

#define X_ELEMS (N_TOK * K_DIM)   // 8388608
#define W_ELEMS (H_DIM * K_DIM)   // 2097152
#define WS_NEED ((size_t)(2 * X_ELEMS + 3 * W_ELEMS) * 2)  // 46,137,344 B

#define XB (X_ELEMS / 8 / 256)    // 4096 prepass blocks for X
#define WB (W_ELEMS / 8 / 256)    // 1024 for W, 1024 for T

#define LOG2E 1.4426950408889634f
#define LN2   0.6931471805599453f

__device__ __forceinline__ unsigned short f2bf(float f) {
    unsigned int u = __float_as_uint(f);
    u += 0x7FFFu + ((u >> 16) & 1u);    // round-to-nearest-even
    return (unsigned short)(u >> 16);
}
__device__ __forceinline__ float bf2f(unsigned short h) {
    return __uint_as_float(((unsigned int)h) << 16);
}

__device__ __forceinline__ void cvt_split(f32x4 a, f32x4 b, short8& vh, short8& vl) {
#pragma unroll
    for (int i = 0; i < 4; ++i) {
        float f = a[i];
        unsigned short h = f2bf(f);
        vh[i] = (short)h;
        vl[i] = (short)f2bf(f - bf2f(h));
    }
#pragma unroll
    for (int i = 0; i < 4; ++i) {
        float f = b[i];
        unsigned short h = f2bf(f);
        vh[i + 4] = (short)h;
        vl[i + 4] = (short)f2bf(f - bf2f(h));
    }
}
__device__ __forceinline__ short8 cvt_hi(f32x4 a, f32x4 b) {
    short8 v;
#pragma unroll
    for (int i = 0; i < 4; ++i) { v[i] = (short)f2bf(a[i]); v[i + 4] = (short)f2bf(b[i]); }
    return v;
}

#define MFMA16(A, B, C) __builtin_amdgcn_mfma_f32_16x16x32_bf16(A, B, C, 0, 0, 0)

// ---------------------------------------------------------------- prepass ---
// X,W -> hi/lo bf16 split; T -> bf16 scaled by log2e (exp2-based softmax).
__global__ __launch_bounds__(256) void prepass_all(
    const float* __restrict__ X, const float* __restrict__ W,
    const float* __restrict__ T,
    unsigned short* __restrict__ XH, unsigned short* __restrict__ XL,
    unsigned short* __restrict__ WH, unsigned short* __restrict__ WL,
    unsigned short* __restrict__ TH)
{
    int b = blockIdx.x;
    if (b < XB + WB) {
        const float* src; unsigned short *hi, *lo; int i;
        if (b < XB) { src = X; hi = XH; lo = XL; i = b * 256 + threadIdx.x; }
        else        { src = W; hi = WH; lo = WL; i = (b - XB) * 256 + threadIdx.x; }
        const float* p = src + (size_t)i * 8;
        f32x4 a = *(const f32x4*)p;
        f32x4 c = *(const f32x4*)(p + 4);
        short8 vh, vl;
        cvt_split(a, c, vh, vl);
        *(short8*)&hi[(size_t)i * 8] = vh;
        *(short8*)&lo[(size_t)i * 8] = vl;
    } else {
        int i = (b - XB - WB) * 256 + threadIdx.x;
        const float* p = T + (size_t)i * 8;
        f32x4 a = *(const f32x4*)p;
        f32x4 c = *(const f32x4*)(p + 4);
#pragma unroll
        for (int j = 0; j < 4; ++j) { a[j] *= LOG2E; c[j] *= LOG2E; }
        *(short8*)&TH[(size_t)i * 8] = cvt_hi(a, c);
    }
}

// ------------------------------------------------------------- main GEMM ----
#define GLL(gp, lp) __builtin_amdgcn_global_load_lds(                      \
        (const __attribute__((address_space(1))) void*)(gp),               \
        (__attribute__((address_space(3))) void*)(lp), 16, 0, 0)

__global__ __launch_bounds__(512) void dend_gemm(
    const unsigned short* __restrict__ XH, const unsigned short* __restrict__ XL,
    const unsigned short* __restrict__ WH, const unsigned short* __restrict__ WL,
    const unsigned short* __restrict__ TH, float* __restrict__ O)
{
    // LDS: W/T only, [128 rows][32 K] shorts, double-buffered = 48 KB
    __shared__ __align__(16) short ldsw[2][3][BH * BK];

    const int tid  = threadIdx.x;
    const int lane = tid & 63;
    const int wv   = tid >> 6;    // 0..7
    const int wm   = wv >> 2;     // 0..1  (64 token-rows each)
    const int wn   = wv & 3;      // 0..3  (32 units each)

    // grid 256 = 32 row-blocks x 8 col-panels; XCD k owns row-blocks
    // [4k,4k+4) (all col panels) -> X slice 2 MB, L2-resident per XCD.
    const int bid     = blockIdx.x;
    const int logical = (bid & 7) * 32 + (bid >> 3);
    const int nb   = logical >> 3;   // 0..31
    const int hb   = logical & 7;    // 0..7
    const int row0 = nb * BM;
    const int col0 = hb * BH;

    // ---- W/T staging (validated r4 layout): GLL linear dest; pre-swizzled
    // global source so slot s of row r holds chunk s ^ ((r>>1)&3).
    const int sc   = (lane & 3) ^ ((lane >> 3) & 3);
    const int wrow = wv * 16 + (lane >> 2);         // 0..127
    const size_t wbase = (size_t)(col0 + wrow) * K_DIM + sc * 8;

#define STAGE(buf, t) do {                                                 \
        const size_t ko = (size_t)(t) * BK;                                \
        GLL(WH + wbase + ko, &ldsw[buf][0][wv << 9]);                      \
        GLL(WL + wbase + ko, &ldsw[buf][1][wv << 9]);                      \
        GLL(TH + wbase + ko, &ldsw[buf][2][wv << 9]);                      \
    } while (0)

    // ---- A (X) direct global->VGPR. 16x16x32 A-frag: lane holds row
    // (lane&15), k = (lane>>4)*8 + i. 4 mi frags x hi/lo.
    size_t arow[4];
#pragma unroll
    for (int mi = 0; mi < 4; ++mi)
        arow[mi] = (size_t)(row0 + wm * 64 + mi * 16 + (lane & 15)) * K_DIM
                 + (lane >> 4) * 8;

#define LOADA(AH, AL, t) do {                                              \
        const size_t ko = (size_t)(t) * BK;                                \
        _Pragma("unroll")                                                  \
        for (int mi = 0; mi < 4; ++mi) {                                   \
            AH[mi] = *(const short8*)&XH[arow[mi] + ko];                   \
            AL[mi] = *(const short8*)&XL[arow[mi] + ko];                   \
        }                                                                  \
    } while (0)

    // ---- B fragment read offsets (validated swizzle, 0 conflicts r1-r6)
    const int g = lane >> 4;
    int b_off[2];
#pragma unroll
    for (int nj = 0; nj < 2; ++nj) {
        int r = wn * 32 + nj * 16 + (lane & 15);    // 0..127
        b_off[nj] = r * BK + (g ^ ((r >> 1) & 3)) * 8;
    }

    const f32x4 zeroc = (f32x4)0.0f;
    f32x4 lin[4][2], num[4][2], den[4][2], win[4][2];
#pragma unroll
    for (int mi = 0; mi < 4; ++mi)
#pragma unroll
        for (int nj = 0; nj < 2; ++nj) {
            lin[mi][nj] = zeroc; num[mi][nj] = zeroc; den[mi][nj] = zeroc;
        }

#define COMPUTE(buf, AH, AL, ZW) do {                                      \
        short8 bwh[2], bwl[2], bth[2];                                     \
        _Pragma("unroll")                                                  \
        for (int nj = 0; nj < 2; ++nj) {                                   \
            bwh[nj] = *(const short8*)&ldsw[buf][0][b_off[nj]];            \
            bwl[nj] = *(const short8*)&ldsw[buf][1][b_off[nj]];            \
            bth[nj] = *(const short8*)&ldsw[buf][2][b_off[nj]];            \
        }                                                                  \
        _Pragma("unroll")                                                  \
        for (int mi = 0; mi < 4; ++mi) {                                   \
            _Pragma("unroll")                                              \
            for (int nj = 0; nj < 2; ++nj) {                               \
                lin[mi][nj] = MFMA16(AH[mi], bwh[nj], lin[mi][nj]);        \
                lin[mi][nj] = MFMA16(AL[mi], bwh[nj], lin[mi][nj]);        \
                lin[mi][nj] = MFMA16(AH[mi], bwl[nj], lin[mi][nj]);        \
                win[mi][nj] = MFMA16(AH[mi], bth[nj], (ZW) ? zeroc : win[mi][nj]); \
            }                                                              \
        }                                                                  \
    } while (0)

    // d = a*log2e  ->  e = exp2(|d|) = exp(|a|); 3 VALU/elem.
#define EPILOG() do {                                                      \
        _Pragma("unroll")                                                  \
        for (int mi = 0; mi < 4; ++mi)                                     \
        _Pragma("unroll")                                                  \
        for (int nj = 0; nj < 2; ++nj)                                     \
        _Pragma("unroll")                                                  \
        for (int i = 0; i < 4; ++i) {                                      \
            float d = win[mi][nj][i];                                      \
            float e = exp2f(fabsf(d));                                     \
            den[mi][nj][i] += e;                                           \
            num[mi][nj][i] = fmaf(e, d, num[mi][nj][i]);                   \
        }                                                                  \
    } while (0)

    short8 ahA[4], alA[4], ahB[4], alB[4];

    LOADA(ahA, alA, 0);
    STAGE(0, 0);
    __syncthreads();

#pragma unroll 1
    for (int w = 0; w < 32; ++w) {
        const int t0 = 2 * w;
        STAGE(1, t0 + 1);
        LOADA(ahB, alB, t0 + 1);
        COMPUTE(0, ahA, alA, true);
        __syncthreads();
        if (t0 + 2 < 64) {
            STAGE(0, t0 + 2);
            LOADA(ahA, alA, t0 + 2);
        }
        COMPUTE(1, ahB, alB, false);
        EPILOG();
        __syncthreads();
    }

    // Final epilogue: g = (num/den)*ln2, silu, multiply, store.
#pragma unroll
    for (int mi = 0; mi < 4; ++mi)
#pragma unroll
        for (int nj = 0; nj < 2; ++nj)
#pragma unroll
            for (int i = 0; i < 4; ++i) {
                float gg   = (num[mi][nj][i] / den[mi][nj][i]) * LN2;
                float gate = gg / (1.0f + __expf(-gg));
                float val  = gate * lin[mi][nj][i];
                int r = row0 + wm * 64 + mi * 16 + (lane >> 4) * 4 + i;
                int c = col0 + wn * 32 + nj * 16 + (lane & 15);
                O[(size_t)r * H_DIM + c] = val;
            }
#undef STAGE
#undef LOADA
#undef COMPUTE
#undef EPILOG
}

// ------------------------------------------------- fallback (round-1 path) --
__global__ __launch_bounds__(512) void dend_fused_v0(
    const float* __restrict__ X, const float* __restrict__ T,
    const float* __restrict__ W, float* __restrict__ O)
{
    __shared__ __align__(16) short lds[2][5][128 * BK];

    const int tid  = threadIdx.x;
    const int lane = tid & 63;
    const int wv   = tid >> 6;
    const int wm   = wv >> 2;
    const int wn   = wv & 3;

    const int bid     = blockIdx.x;
    const int logical = (bid & 7) * 32 + (bid >> 3);
    const int hb   = logical >> 5;
    const int nb   = logical & 31;
    const int row0 = nb * 128;
    const int col0 = hb * 128;

    const int srow  = tid >> 2;
    const int schn  = tid & 3;
    const int sslot = schn ^ ((srow >> 1) & 3);
    const int swoff = srow * BK + sslot * 8;

    const float* gx = X + (size_t)(row0 + srow) * K_DIM + schn * 8;
    const float* gw = W + (size_t)(col0 + srow) * K_DIM + schn * 8;
    const float* gt = T + (size_t)(col0 + srow) * K_DIM + schn * 8;

    const int g = lane >> 4;
    int a_off[4], b_off[2];
#pragma unroll
    for (int mi = 0; mi < 4; ++mi) {
        int r = wm * 64 + mi * 16 + (lane & 15);
        a_off[mi] = r * BK + (g ^ ((r >> 1) & 3)) * 8;
    }
#pragma unroll
    for (int nj = 0; nj < 2; ++nj) {
        int r = wn * 32 + nj * 16 + (lane & 15);
        b_off[nj] = r * BK + (g ^ ((r >> 1) & 3)) * 8;
    }

    const f32x4 zeroc = (f32x4)0.0f;
    f32x4 lin[4][2], num[4][2], den[4][2], win[4][2];
#pragma unroll
    for (int mi = 0; mi < 4; ++mi)
#pragma unroll
        for (int nj = 0; nj < 2; ++nj) {
            lin[mi][nj] = zeroc; num[mi][nj] = zeroc; den[mi][nj] = zeroc;
        }

    f32x4 rx0, rx1, rw0, rw1, rt0, rt1;

#define LOADS(t) do {                                                   \
        const float* px = gx + (size_t)(t) * BK;                        \
        const float* pw = gw + (size_t)(t) * BK;                        \
        const float* pt = gt + (size_t)(t) * BK;                        \
        rx0 = *(const f32x4*)(px); rx1 = *(const f32x4*)(px + 4);       \
        rw0 = *(const f32x4*)(pw); rw1 = *(const f32x4*)(pw + 4);       \
        rt0 = *(const f32x4*)(pt); rt1 = *(const f32x4*)(pt + 4);       \
    } while (0)

#define WRITE(buf) do {                                                 \
        short8 vh, vl;                                                  \
        cvt_split(rx0, rx1, vh, vl);                                    \
        *(short8*)&lds[buf][0][swoff] = vh;                             \
        *(short8*)&lds[buf][1][swoff] = vl;                             \
        cvt_split(rw0, rw1, vh, vl);                                    \
        *(short8*)&lds[buf][2][swoff] = vh;                             \
        *(short8*)&lds[buf][3][swoff] = vl;                             \
        *(short8*)&lds[buf][4][swoff] = cvt_hi(rt0, rt1);               \
    } while (0)

#define COMPUTE(buf, ZW) do {                                           \
        short8 bwh[2], bwl[2], bth[2];                                  \
        _Pragma("unroll")                                               \
        for (int nj = 0; nj < 2; ++nj) {                                \
            bwh[nj] = *(const short8*)&lds[buf][2][b_off[nj]];          \
            bwl[nj] = *(const short8*)&lds[buf][3][b_off[nj]];          \
            bth[nj] = *(const short8*)&lds[buf][4][b_off[nj]];          \
        }                                                               \
        _Pragma("unroll")                                               \
        for (int mi = 0; mi < 4; ++mi) {                                \
            short8 ah = *(const short8*)&lds[buf][0][a_off[mi]];        \
            short8 al = *(const short8*)&lds[buf][1][a_off[mi]];        \
            _Pragma("unroll")                                           \
            for (int nj = 0; nj < 2; ++nj) {                            \
                lin[mi][nj] = MFMA16(ah, bwh[nj], lin[mi][nj]);         \
                lin[mi][nj] = MFMA16(al, bwh[nj], lin[mi][nj]);         \
                lin[mi][nj] = MFMA16(ah, bwl[nj], lin[mi][nj]);         \
                win[mi][nj] = MFMA16(ah, bth[nj], (ZW) ? zeroc : win[mi][nj]); \
            }                                                           \
        }                                                               \
    } while (0)

#define EPILOG() do {                                                   \
        _Pragma("unroll")                                               \
        for (int mi = 0; mi < 4; ++mi)                                  \
        _Pragma("unroll")                                               \
        for (int nj = 0; nj < 2; ++nj)                                  \
        _Pragma("unroll")                                               \
        for (int i = 0; i < 4; ++i) {                                   \
            float d = win[mi][nj][i];                                   \
            float e = __expf(fabsf(d));                                 \
            den[mi][nj][i] += e;                                        \
            num[mi][nj][i] = fmaf(e, d, num[mi][nj][i]);                \
        }                                                               \
    } while (0)

    LOADS(0);
    WRITE(0);
    __syncthreads();

#pragma unroll 1
    for (int w = 0; w < 32; ++w) {
        const int t0 = 2 * w;
        LOADS(t0 + 1);
        COMPUTE(0, true);
        __syncthreads();
        WRITE(1);
        __syncthreads();
        const bool more = (w < 31);
        if (more) LOADS(t0 + 2);
        COMPUTE(1, false);
        EPILOG();
        __syncthreads();
        if (more) WRITE(0);
        __syncthreads();
    }

#pragma unroll
    for (int mi = 0; mi < 4; ++mi)
#pragma unroll
        for (int nj = 0; nj < 2; ++nj)
#pragma unroll
            for (int i = 0; i < 4; ++i) {
                float gg   = num[mi][nj][i] / den[mi][nj][i];
                float gate = gg / (1.0f + __expf(-gg));
                float val  = gate * lin[mi][nj][i];
                int r = row0 + wm * 64 + mi * 16 + (lane >> 4) * 4 + i;
                int c = col0 + wn * 32 + nj * 16 + (lane & 15);
                O[(size_t)r * H_DIM + c] = val;
            }
#undef LOADS
#undef WRITE
#undef COMPUTE
#undef EPILOG
}

extern "C" void kernel_launch(void* const* d_in, const int* in_sizes, int n_in,
                              void* d_out, int out_size, void* d_ws, size_t ws_size,
                              hipStream_t stream) {
    const float* X = (const float*)d_in[0];   // x [4096,2048]
    const float* T = (const float*)d_in[1];   // template_flat [1024,2048]
    const float* W = (const float*)d_in[2];   // weights [1024,2048]
    float* O = (float*)d_out;                 // [4096,1024]
    (void)in_sizes; (void)n_in; (void)out_size;

    if (ws_size >= WS_NEED) {
        unsigned short* XHp = (unsigned short*)d_ws;
        unsigned short* XLp = XHp + X_ELEMS;
        unsigned short* WHp = XLp + X_ELEMS;
        unsigned short* WLp = WHp + W_ELEMS;
        unsigned short* THp = WLp + W_ELEMS;
        prepass_all<<<XB + 2 * WB, 256, 0, stream>>>(X, W, T, XHp, XLp, WHp, WLp, THp);
        dend_gemm<<<256, 512, 0, stream>>>(XHp, XLp, WHp, WLp, THp, O);
    } else {
        dend_fused_v0<<<256, 512, 0, stream>>>(X, T, W, O);
    }
}

// Round 8
// 116.075 us; speedup vs baseline: 1.8350x; 1.8350x over previous
//
#include <hip/hip_runtime.h>
#include <hip/hip_bf16.h>

// DendriticLayerSiLU: out = silu(softmax-gated template proj) * (x @ W^T)
// N=4096 tokens, K=2048, H=1024, 32 windows of 64.
// Round 8: faithful T3+T4 port. r2 geometry (128x128, BK=32, 8 waves) +
// 4-deep LDS (160 KB) + 4 phases per K-step (fine ds_read/GLL/MFMA
// interleave, double barrier per phase, lgkmcnt(0)+sched_barrier) +
// one counted vmcnt(10) per K-step (T4) + setprio around MFMA (T5).
// EPILOG (exp2-based, log2e folded into T prepass) sliced per-mi into
// the phases of the following even step; den over-count corrected by -1.

typedef __attribute__((ext_vector_type(8))) short short8;
typedef __attribute__((ext_vector_type(4))) float f32x4;

#define N_TOK 4096
#define K_DIM 2048
#define H_DIM 1024
#define BM 128
#define BH 128
#define BK 32
#define LDSZ (BM * BK)

#define X_ELEMS (N_TOK * K_DIM)   // 8388608
#define W_ELEMS (H_DIM * K_DIM)   // 2097152
#define WS_NEED ((size_t)(2 * X_ELEMS + 3 * W_ELEMS) * 2)  // 46,137,344 B

#define XB (X_ELEMS / 8 / 256)    // 4096 prepass blocks for X
#define WB (W_ELEMS / 8 / 256)    // 1024 for W, 1024 for T

#define LOG2E 1.4426950408889634f
#define LN2   0.6931471805599453f

__device__ __forceinline__ unsigned short f2bf(float f) {
    unsigned int u = __float_as_uint(f);
    u += 0x7FFFu + ((u >> 16) & 1u);    // round-to-nearest-even
    return (unsigned short)(u >> 16);
}
__device__ __forceinline__ float bf2f(unsigned short h) {
    return __uint_as_float(((unsigned int)h) << 16);
}

__device__ __forceinline__ void cvt_split(f32x4 a, f32x4 b, short8& vh, short8& vl) {
#pragma unroll
    for (int i = 0; i < 4; ++i) {
        float f = a[i];
        unsigned short h = f2bf(f);
        vh[i] = (short)h;
        vl[i] = (short)f2bf(f - bf2f(h));
    }
#pragma unroll
    for (int i = 0; i < 4; ++i) {
        float f = b[i];
        unsigned short h = f2bf(f);
        vh[i + 4] = (short)h;
        vl[i + 4] = (short)f2bf(f - bf2f(h));
    }
}
__device__ __forceinline__ short8 cvt_hi(f32x4 a, f32x4 b) {
    short8 v;
#pragma unroll
    for (int i = 0; i < 4; ++i) { v[i] = (short)f2bf(a[i]); v[i + 4] = (short)f2bf(b[i]); }
    return v;
}

#define MFMA16(A, B, C) __builtin_amdgcn_mfma_f32_16x16x32_bf16(A, B, C, 0, 0, 0)

// ---------------------------------------------------------------- prepass ---
// X,W -> hi/lo bf16 split; T -> bf16 scaled by log2e (exp2-based softmax).
__global__ __launch_bounds__(256) void prepass_all(
    const float* __restrict__ X, const float* __restrict__ W,
    const float* __restrict__ T,
    unsigned short* __restrict__ XH, unsigned short* __restrict__ XL,
    unsigned short* __restrict__ WH, unsigned short* __restrict__ WL,
    unsigned short* __restrict__ TH)
{
    int b = blockIdx.x;
    if (b < XB + WB) {
        const float* src; unsigned short *hi, *lo; int i;
        if (b < XB) { src = X; hi = XH; lo = XL; i = b * 256 + threadIdx.x; }
        else        { src = W; hi = WH; lo = WL; i = (b - XB) * 256 + threadIdx.x; }
        const float* p = src + (size_t)i * 8;
        f32x4 a = *(const f32x4*)p;
        f32x4 c = *(const f32x4*)(p + 4);
        short8 vh, vl;
        cvt_split(a, c, vh, vl);
        *(short8*)&hi[(size_t)i * 8] = vh;
        *(short8*)&lo[(size_t)i * 8] = vl;
    } else {
        int i = (b - XB - WB) * 256 + threadIdx.x;
        const float* p = T + (size_t)i * 8;
        f32x4 a = *(const f32x4*)p;
        f32x4 c = *(const f32x4*)(p + 4);
#pragma unroll
        for (int j = 0; j < 4; ++j) { a[j] *= LOG2E; c[j] *= LOG2E; }
        *(short8*)&TH[(size_t)i * 8] = cvt_hi(a, c);
    }
}

// ------------------------------------------------------------- main GEMM ----
#define GLL(gp, lp) __builtin_amdgcn_global_load_lds(                      \
        (const __attribute__((address_space(1))) void*)(gp),               \
        (__attribute__((address_space(3))) void*)(lp), 16, 0, 0)

#define VM10 asm volatile("s_waitcnt vmcnt(10)" ::: "memory")
#define VM5  asm volatile("s_waitcnt vmcnt(5)"  ::: "memory")
#define VM0  asm volatile("s_waitcnt vmcnt(0)"  ::: "memory")
#define NOP  ((void)0)

__global__ __launch_bounds__(512) void dend_gemm(
    const unsigned short* __restrict__ XH, const unsigned short* __restrict__ XL,
    const unsigned short* __restrict__ WH, const unsigned short* __restrict__ WL,
    const unsigned short* __restrict__ TH, float* __restrict__ O)
{
    // 4-deep pipeline: arrays 0=x_hi 1=x_lo 2=w_hi 3=w_lo 4=t_hi ; 160 KB
    __shared__ __align__(16) short lds[4][5][LDSZ];

    const int tid  = threadIdx.x;
    const int lane = tid & 63;
    const int wv   = tid >> 6;    // 0..7
    const int wm   = wv >> 2;     // 0..1  (64 token-rows each)
    const int wn   = wv & 3;      // 0..3  (32 units each)

    const int bid     = blockIdx.x;
    const int logical = (bid & 7) * 32 + (bid >> 3);   // XCD-chunked swizzle
    const int hb   = logical >> 5;   // 0..7
    const int nb   = logical & 31;   // 0..31
    const int row0 = nb * BM;
    const int col0 = hb * BH;

    // Staging (validated r2 layout): GLL linear dest; pre-swizzled global
    // source so slot s of row r holds chunk s ^ ((r>>1)&3).
    const int srow = (wv << 4) + (lane >> 2);
    const int sc   = (lane & 3) ^ ((lane >> 3) & 3);
    const size_t xbase = (size_t)(row0 + srow) * K_DIM + sc * 8;
    const size_t wbase = (size_t)(col0 + srow) * K_DIM + sc * 8;

#define ST_XH(sb, ko) GLL(XH + xbase + (ko), &lds[sb][0][wv << 9])
#define ST_XL(sb, ko) GLL(XL + xbase + (ko), &lds[sb][1][wv << 9])
#define ST_WH(sb, ko) GLL(WH + wbase + (ko), &lds[sb][2][wv << 9])
#define ST_WL(sb, ko) GLL(WL + wbase + (ko), &lds[sb][3][wv << 9])
#define ST_TH(sb, ko) GLL(TH + wbase + (ko), &lds[sb][4][wv << 9])

    // Fragment read offsets (validated swizzle, 0 conflicts in r1-r6)
    const int g = lane >> 4;
    int a_off[4], b_off[2];
#pragma unroll
    for (int mi = 0; mi < 4; ++mi) {
        int r = wm * 64 + mi * 16 + (lane & 15);
        a_off[mi] = r * BK + (g ^ ((r >> 1) & 3)) * 8;
    }
#pragma unroll
    for (int nj = 0; nj < 2; ++nj) {
        int r = wn * 32 + nj * 16 + (lane & 15);
        b_off[nj] = r * BK + (g ^ ((r >> 1) & 3)) * 8;
    }

    const f32x4 zeroc = (f32x4)0.0f;
    f32x4 lin[4][2], num[4][2], den[4][2], win[4][2];
#pragma unroll
    for (int mi = 0; mi < 4; ++mi)
#pragma unroll
        for (int nj = 0; nj < 2; ++nj) {
            lin[mi][nj] = zeroc; num[mi][nj] = zeroc;
            den[mi][nj] = zeroc; win[mi][nj] = zeroc;
        }

    short8 bwh[2], bwl[2], bth[2];   // B-frags, live across a step's phases

    // EPILOG slice for one mi (3 VALU/elem; exp2(|d|) with log2e pre-folded)
#define EPIC(mi) do {                                                      \
        _Pragma("unroll")                                                  \
        for (int nj = 0; nj < 2; ++nj)                                     \
        _Pragma("unroll")                                                  \
        for (int i = 0; i < 4; ++i) {                                      \
            float d = win[mi][nj][i];                                      \
            float e = exp2f(fabsf(d));                                     \
            den[mi][nj][i] += e;                                           \
            num[mi][nj][i] = fmaf(e, d, num[mi][nj][i]);                   \
        }                                                                  \
    } while (0)

    // One phase: reads + GLL issue -> barrier -> lgkmcnt(0) -> EPI slice ->
    // setprio MFMA cluster -> [vmcnt] -> barrier.  (template from m201)
#define PHASE(buf, mi, ZW, STG, EPI, VMW) do {                             \
        short8 ah = *(const short8*)&lds[buf][0][a_off[mi]];               \
        short8 al = *(const short8*)&lds[buf][1][a_off[mi]];               \
        if ((mi) == 0) {                                                   \
            bwh[0] = *(const short8*)&lds[buf][2][b_off[0]];               \
            bwh[1] = *(const short8*)&lds[buf][2][b_off[1]];               \
            bwl[0] = *(const short8*)&lds[buf][3][b_off[0]];               \
            bwl[1] = *(const short8*)&lds[buf][3][b_off[1]];               \
            bth[0] = *(const short8*)&lds[buf][4][b_off[0]];               \
            bth[1] = *(const short8*)&lds[buf][4][b_off[1]];               \
        }                                                                  \
        STG;                                                               \
        __builtin_amdgcn_sched_barrier(0);                                 \
        __builtin_amdgcn_s_barrier();                                      \
        asm volatile("s_waitcnt lgkmcnt(0)" ::: "memory");                 \
        __builtin_amdgcn_sched_barrier(0);                                 \
        EPI;                                                               \
        __builtin_amdgcn_s_setprio(1);                                     \
        _Pragma("unroll")                                                  \
        for (int nj = 0; nj < 2; ++nj) {                                   \
            lin[mi][nj] = MFMA16(ah, bwh[nj], lin[mi][nj]);                \
            lin[mi][nj] = MFMA16(al, bwh[nj], lin[mi][nj]);                \
            lin[mi][nj] = MFMA16(ah, bwl[nj], lin[mi][nj]);                \
            win[mi][nj] = MFMA16(ah, bth[nj], (ZW) ? zeroc : win[mi][nj]); \
        }                                                                  \
        __builtin_amdgcn_s_setprio(0);                                     \
        __builtin_amdgcn_sched_barrier(0);                                 \
        VMW;                                                               \
        __builtin_amdgcn_s_barrier();                                      \
    } while (0)

    // One K-step = 4 phases; staging for step t+3 distributed 2/1/1/1.
#define STEPX(buf, ZW, E0, E1, E2, E3, S0, S1, S2, S3, VMW) do {           \
        PHASE(buf, 0, ZW, S0, E0, NOP);                                    \
        PHASE(buf, 1, ZW, S1, E1, NOP);                                    \
        PHASE(buf, 2, ZW, S2, E2, NOP);                                    \
        PHASE(buf, 3, ZW, S3, E3, VMW);                                    \
    } while (0)

    // Prologue: stage tiles 0,1,2 (15 GLL); certify tile 0 (10 stay in flight)
    ST_XH(0, 0); ST_XL(0, 0); ST_WH(0, 0); ST_WL(0, 0); ST_TH(0, 0);
    ST_XH(1, BK); ST_XL(1, BK); ST_WH(1, BK); ST_WL(1, BK); ST_TH(1, BK);
    ST_XH(2, 2 * BK); ST_XL(2, 2 * BK); ST_WH(2, 2 * BK); ST_WL(2, 2 * BK); ST_TH(2, 2 * BK);
    VM10;
    __builtin_amdgcn_s_barrier();

    // Main loop: steps 0..59 in even/odd pairs; stage t+3 / t+4; vmcnt(10)
    // at each step's last phase certifies the NEXT step's tile while 10
    // newer loads stay in flight (T4: never drain to 0 in-loop).
#pragma unroll 1
    for (int t = 0; t < 60; t += 2) {
        const int b0 = t & 3, b1 = (t + 1) & 3;
        const int s0 = (t + 3) & 3, s1 = (t + 4) & 3;
        const size_t k0 = (size_t)(t + 3) * BK, k1 = (size_t)(t + 4) * BK;
        STEPX(b0, true, EPIC(0), EPIC(1), EPIC(2), EPIC(3),
              (ST_XH(s0, k0), ST_XL(s0, k0)), ST_WH(s0, k0), ST_WL(s0, k0),
              ST_TH(s0, k0), VM10);
        STEPX(b1, false, NOP, NOP, NOP, NOP,
              (ST_XH(s1, k1), ST_XL(s1, k1)), ST_WH(s1, k1), ST_WL(s1, k1),
              ST_TH(s1, k1), VM10);
    }
    // Tail: step 60 stages tile 63; drain vmcnt 10 -> 5 -> 0.
    {
        const size_t k63 = (size_t)63 * BK;
        STEPX(0, true, EPIC(0), EPIC(1), EPIC(2), EPIC(3),
              (ST_XH(3, k63), ST_XL(3, k63)), ST_WH(3, k63), ST_WL(3, k63),
              ST_TH(3, k63), VM10);
        STEPX(1, false, NOP, NOP, NOP, NOP, NOP, NOP, NOP, NOP, VM5);
        STEPX(2, true, EPIC(0), EPIC(1), EPIC(2), EPIC(3), NOP, NOP, NOP, NOP, VM0);
        STEPX(3, false, NOP, NOP, NOP, NOP, NOP, NOP, NOP, NOP, NOP);
    }
    // Final window's EPILOG.
    EPIC(0); EPIC(1); EPIC(2); EPIC(3);

    // Final epilogue: g = (num/(den-1))*ln2 (den has +1 from the t=0
    // spurious slice on zero-inited win), silu, multiply, store.
#pragma unroll
    for (int mi = 0; mi < 4; ++mi)
#pragma unroll
        for (int nj = 0; nj < 2; ++nj)
#pragma unroll
            for (int i = 0; i < 4; ++i) {
                float dd   = den[mi][nj][i] - 1.0f;
                float gg   = (num[mi][nj][i] / dd) * LN2;
                float gate = gg / (1.0f + __expf(-gg));
                float val  = gate * lin[mi][nj][i];
                int r = row0 + wm * 64 + mi * 16 + (lane >> 4) * 4 + i;
                int c = col0 + wn * 32 + nj * 16 + (lane & 15);
                O[(size_t)r * H_DIM + c] = val;
            }
#undef PHASE
#undef STEPX
#undef EPIC
#undef ST_XH
#undef ST_XL
#undef ST_WH
#undef ST_WL
#undef ST_TH
}

// ------------------------------------------------- fallback (round-1 path) --
__global__ __launch_bounds__(512) void dend_fused_v0(
    const float* __restrict__ X, const float* __restrict__ T,
    const float* __restrict__ W, float* __restrict__ O)
{
    __shared__ __align__(16) short lds[2][5][LDSZ];

    const int tid  = threadIdx.x;
    const int lane = tid & 63;
    const int wv   = tid >> 6;
    const int wm   = wv >> 2;
    const int wn   = wv & 3;

    const int bid     = blockIdx.x;
    const int logical = (bid & 7) * 32 + (bid >> 3);
    const int hb   = logical >> 5;
    const int nb   = logical & 31;
    const int row0 = nb * 128;
    const int col0 = hb * 128;

    const int srow  = tid >> 2;
    const int schn  = tid & 3;
    const int sslot = schn ^ ((srow >> 1) & 3);
    const int swoff = srow * BK + sslot * 8;

    const float* gx = X + (size_t)(row0 + srow) * K_DIM + schn * 8;
    const float* gw = W + (size_t)(col0 + srow) * K_DIM + schn * 8;
    const float* gt = T + (size_t)(col0 + srow) * K_DIM + schn * 8;

    const int g = lane >> 4;
    int a_off[4], b_off[2];
#pragma unroll
    for (int mi = 0; mi < 4; ++mi) {
        int r = wm * 64 + mi * 16 + (lane & 15);
        a_off[mi] = r * BK + (g ^ ((r >> 1) & 3)) * 8;
    }
#pragma unroll
    for (int nj = 0; nj < 2; ++nj) {
        int r = wn * 32 + nj * 16 + (lane & 15);
        b_off[nj] = r * BK + (g ^ ((r >> 1) & 3)) * 8;
    }

    const f32x4 zeroc = (f32x4)0.0f;
    f32x4 lin[4][2], num[4][2], den[4][2], win[4][2];
#pragma unroll
    for (int mi = 0; mi < 4; ++mi)
#pragma unroll
        for (int nj = 0; nj < 2; ++nj) {
            lin[mi][nj] = zeroc; num[mi][nj] = zeroc; den[mi][nj] = zeroc;
        }

    f32x4 rx0, rx1, rw0, rw1, rt0, rt1;

#define LOADS(t) do {                                                   \
        const float* px = gx + (size_t)(t) * BK;                        \
        const float* pw = gw + (size_t)(t) * BK;                        \
        const float* pt = gt + (size_t)(t) * BK;                        \
        rx0 = *(const f32x4*)(px); rx1 = *(const f32x4*)(px + 4);       \
        rw0 = *(const f32x4*)(pw); rw1 = *(const f32x4*)(pw + 4);       \
        rt0 = *(const f32x4*)(pt); rt1 = *(const f32x4*)(pt + 4);       \
    } while (0)

#define WRITE(buf) do {                                                 \
        short8 vh, vl;                                                  \
        cvt_split(rx0, rx1, vh, vl);                                    \
        *(short8*)&lds[buf][0][swoff] = vh;                             \
        *(short8*)&lds[buf][1][swoff] = vl;                             \
        cvt_split(rw0, rw1, vh, vl);                                    \
        *(short8*)&lds[buf][2][swoff] = vh;                             \
        *(short8*)&lds[buf][3][swoff] = vl;                             \
        *(short8*)&lds[buf][4][swoff] = cvt_hi(rt0, rt1);               \
    } while (0)

#define COMPUTE(buf, ZW) do {                                           \
        short8 bwh[2], bwl[2], bth[2];                                  \
        _Pragma("unroll")                                               \
        for (int nj = 0; nj < 2; ++nj) {                                \
            bwh[nj] = *(const short8*)&lds[buf][2][b_off[nj]];          \
            bwl[nj] = *(const short8*)&lds[buf][3][b_off[nj]];          \
            bth[nj] = *(const short8*)&lds[buf][4][b_off[nj]];          \
        }                                                               \
        _Pragma("unroll")                                               \
        for (int mi = 0; mi < 4; ++mi) {                                \
            short8 ah = *(const short8*)&lds[buf][0][a_off[mi]];        \
            short8 al = *(const short8*)&lds[buf][1][a_off[mi]];        \
            _Pragma("unroll")                                           \
            for (int nj = 0; nj < 2; ++nj) {                            \
                lin[mi][nj] = MFMA16(ah, bwh[nj], lin[mi][nj]);         \
                lin[mi][nj] = MFMA16(al, bwh[nj], lin[mi][nj]);         \
                lin[mi][nj] = MFMA16(ah, bwl[nj], lin[mi][nj]);         \
                win[mi][nj] = MFMA16(ah, bth[nj], (ZW) ? zeroc : win[mi][nj]); \
            }                                                           \
        }                                                               \
    } while (0)

#define EPILOG() do {                                                   \
        _Pragma("unroll")                                               \
        for (int mi = 0; mi < 4; ++mi)                                  \
        _Pragma("unroll")                                               \
        for (int nj = 0; nj < 2; ++nj)                                  \
        _Pragma("unroll")                                               \
        for (int i = 0; i < 4; ++i) {                                   \
            float d = win[mi][nj][i];                                   \
            float e = __expf(fabsf(d));                                 \
            den[mi][nj][i] += e;                                        \
            num[mi][nj][i] = fmaf(e, d, num[mi][nj][i]);                \
        }                                                               \
    } while (0)

    LOADS(0);
    WRITE(0);
    __syncthreads();

#pragma unroll 1
    for (int w = 0; w < 32; ++w) {
        const int t0 = 2 * w;
        LOADS(t0 + 1);
        COMPUTE(0, true);
        __syncthreads();
        WRITE(1);
        __syncthreads();
        const bool more = (w < 31);
        if (more) LOADS(t0 + 2);
        COMPUTE(1, false);
        EPILOG();
        __syncthreads();
        if (more) WRITE(0);
        __syncthreads();
    }

#pragma unroll
    for (int mi = 0; mi < 4; ++mi)
#pragma unroll
        for (int nj = 0; nj < 2; ++nj)
#pragma unroll
            for (int i = 0; i < 4; ++i) {
                float gg   = num[mi][nj][i] / den[mi][nj][i];
                float gate = gg / (1.0f + __expf(-gg));
                float val  = gate * lin[mi][nj][i];
                int r = row0 + wm * 64 + mi * 16 + (lane >> 4) * 4 + i;
                int c = col0 + wn * 32 + nj * 16 + (lane & 15);
                O[(size_t)r * H_DIM + c] = val;
            }
#undef LOADS
#undef WRITE
#undef COMPUTE
#undef EPILOG
}

extern "C" void kernel_launch(void* const* d_in, const int* in_sizes, int n_in,
                              void* d_out, int out_size, void* d_ws, size_t ws_size,
                              hipStream_t stream) {
    const float* X = (const float*)d_in[0];   // x [4096,2048]
    const float* T = (const float*)d_in[1];   // template_flat [1024,2048]
    const float* W = (const float*)d_in[2];   // weights [1024,2048]
    float* O = (float*)d_out;                 // [4096,1024]
    (void)in_sizes; (void)n_in; (void)out_size;

    if (ws_size >= WS_NEED) {
        unsigned short* XHp = (unsigned short*)d_ws;
        unsigned short* XLp = XHp + X_ELEMS;
        unsigned short* WHp = XLp + X_ELEMS;
        unsigned short* WLp = WHp + W_ELEMS;
        unsigned short* THp = WLp + W_ELEMS;
        prepass_all<<<XB + 2 * WB, 256, 0, stream>>>(X, W, T, XHp, XLp, WHp, WLp, THp);
        dend_gemm<<<256, 512, 0, stream>>>(XHp, XLp, WHp, WLp, THp, O);
    } else {
        dend_fused_v0<<<256, 512, 0, stream>>>(X, T, W, O);
    }
}

// Round 9
// 107.231 us; speedup vs baseline: 1.9863x; 1.0825x over previous
//
#include <hip/hip_runtime.h>
#include <hip/hip_bf16.h>

// DendriticLayerSiLU: out = silu(softmax-gated template proj) * (x @ W^T)
// N=4096 tokens, K=2048, H=1024, 32 windows of 64.
// Round 9: BK=64 (window == K-step). One barrier per K=64 (half of r2),
// inline per-step EPILOG (no win-carry), 5 arrays x [128][64] x 2buf =
// 160 KB LDS, new conflict-free swizzle slot = chunk ^ (row&7) with
// matching GLL source pre-swizzle. Gate uses exp2 with log2e folded into
// the T prepass (validated r8). Everything else = validated r2 lineage.

typedef __attribute__((ext_vector_type(8))) short short8;
typedef __attribute__((ext_vector_type(4))) float f32x4;

#define N_TOK 4096
#define K_DIM 2048
#define H_DIM 1024
#define BM 128
#define BH 128
#define BK 64
#define LDSZ (BM * BK)            // 8192 shorts = 16 KB per array

#define X_ELEMS (N_TOK * K_DIM)   // 8388608
#define W_ELEMS (H_DIM * K_DIM)   // 2097152
#define WS_NEED ((size_t)(2 * X_ELEMS + 3 * W_ELEMS) * 2)  // 46,137,344 B

#define XB (X_ELEMS / 8 / 256)    // 4096 prepass blocks for X
#define WB (W_ELEMS / 8 / 256)    // 1024 for W, 1024 for T

#define LOG2E 1.4426950408889634f
#define LN2   0.6931471805599453f

__device__ __forceinline__ unsigned short f2bf(float f) {
    unsigned int u = __float_as_uint(f);
    u += 0x7FFFu + ((u >> 16) & 1u);    // round-to-nearest-even
    return (unsigned short)(u >> 16);
}
__device__ __forceinline__ float bf2f(unsigned short h) {
    return __uint_as_float(((unsigned int)h) << 16);
}

__device__ __forceinline__ void cvt_split(f32x4 a, f32x4 b, short8& vh, short8& vl) {
#pragma unroll
    for (int i = 0; i < 4; ++i) {
        float f = a[i];
        unsigned short h = f2bf(f);
        vh[i] = (short)h;
        vl[i] = (short)f2bf(f - bf2f(h));
    }
#pragma unroll
    for (int i = 0; i < 4; ++i) {
        float f = b[i];
        unsigned short h = f2bf(f);
        vh[i + 4] = (short)h;
        vl[i + 4] = (short)f2bf(f - bf2f(h));
    }
}
__device__ __forceinline__ short8 cvt_hi(f32x4 a, f32x4 b) {
    short8 v;
#pragma unroll
    for (int i = 0; i < 4; ++i) { v[i] = (short)f2bf(a[i]); v[i + 4] = (short)f2bf(b[i]); }
    return v;
}

#define MFMA16(A, B, C) __builtin_amdgcn_mfma_f32_16x16x32_bf16(A, B, C, 0, 0, 0)

// ---------------------------------------------------------------- prepass ---
// X,W -> hi/lo bf16 split; T -> bf16 scaled by log2e (exp2-based softmax).
__global__ __launch_bounds__(256) void prepass_all(
    const float* __restrict__ X, const float* __restrict__ W,
    const float* __restrict__ T,
    unsigned short* __restrict__ XH, unsigned short* __restrict__ XL,
    unsigned short* __restrict__ WH, unsigned short* __restrict__ WL,
    unsigned short* __restrict__ TH)
{
    int b = blockIdx.x;
    if (b < XB + WB) {
        const float* src; unsigned short *hi, *lo; int i;
        if (b < XB) { src = X; hi = XH; lo = XL; i = b * 256 + threadIdx.x; }
        else        { src = W; hi = WH; lo = WL; i = (b - XB) * 256 + threadIdx.x; }
        const float* p = src + (size_t)i * 8;
        f32x4 a = *(const f32x4*)p;
        f32x4 c = *(const f32x4*)(p + 4);
        short8 vh, vl;
        cvt_split(a, c, vh, vl);
        *(short8*)&hi[(size_t)i * 8] = vh;
        *(short8*)&lo[(size_t)i * 8] = vl;
    } else {
        int i = (b - XB - WB) * 256 + threadIdx.x;
        const float* p = T + (size_t)i * 8;
        f32x4 a = *(const f32x4*)p;
        f32x4 c = *(const f32x4*)(p + 4);
#pragma unroll
        for (int j = 0; j < 4; ++j) { a[j] *= LOG2E; c[j] *= LOG2E; }
        *(short8*)&TH[(size_t)i * 8] = cvt_hi(a, c);
    }
}

// ------------------------------------------------------------- main GEMM ----
#define GLL(gp, lp) __builtin_amdgcn_global_load_lds(                      \
        (const __attribute__((address_space(1))) void*)(gp),               \
        (__attribute__((address_space(3))) void*)(lp), 16, 0, 0)

__global__ __launch_bounds__(512) void dend_gemm(
    const unsigned short* __restrict__ XH, const unsigned short* __restrict__ XL,
    const unsigned short* __restrict__ WH, const unsigned short* __restrict__ WL,
    const unsigned short* __restrict__ TH, float* __restrict__ O)
{
    // arrays: 0=x_hi 1=x_lo 2=w_hi 3=w_lo 4=t_hi ; [128][64] shorts each;
    // double-buffered -> 160 KB (full CU LDS, 1 block/CU by design).
    __shared__ __align__(16) short lds[2][5][LDSZ];

    const int tid  = threadIdx.x;
    const int lane = tid & 63;
    const int wv   = tid >> 6;    // 0..7
    const int wm   = wv >> 2;     // 0..1  (64 token-rows each)
    const int wn   = wv & 3;      // 0..3  (32 units each)

    const int bid     = blockIdx.x;
    const int logical = (bid & 7) * 32 + (bid >> 3);   // XCD-chunked swizzle
    const int hb   = logical >> 5;   // 0..7
    const int nb   = logical & 31;   // 0..31
    const int row0 = nb * BM;
    const int col0 = hb * BH;

    // ---- staging: row = 64 shorts = 8 chunks of 16B. Swizzle:
    //   content(row, slot) = logical chunk  slot ^ (row & 7).
    // GLL (1 KB linear): lane l -> row +(l>>3), slot l&7  =>
    //   source chunk = (l&7) ^ (l>>3).  Two GLLs per 16-row wave stripe.
    const int srow8 = lane >> 3;                 // 0..7
    const int schk  = (lane & 7) ^ srow8;        // pre-swizzled source chunk
    const size_t xbase = (size_t)(row0 + wv * 16 + srow8) * K_DIM + schk * 8;
    const size_t wbase = (size_t)(col0 + wv * 16 + srow8) * K_DIM + schk * 8;
    const size_t rstep8 = (size_t)8 * K_DIM;     // +8 rows
    const int dst0 = (wv * 16) * BK;             // short index of stripe row 0
    const int dst1 = dst0 + 8 * BK;

#define STAGE(buf, t) do {                                                 \
        const size_t ko = (size_t)(t) * BK;                                \
        GLL(XH + xbase + ko,          &lds[buf][0][dst0]);                 \
        GLL(XH + xbase + rstep8 + ko, &lds[buf][0][dst1]);                 \
        GLL(XL + xbase + ko,          &lds[buf][1][dst0]);                 \
        GLL(XL + xbase + rstep8 + ko, &lds[buf][1][dst1]);                 \
        GLL(WH + wbase + ko,          &lds[buf][2][dst0]);                 \
        GLL(WH + wbase + rstep8 + ko, &lds[buf][2][dst1]);                 \
        GLL(WL + wbase + ko,          &lds[buf][3][dst0]);                 \
        GLL(WL + wbase + rstep8 + ko, &lds[buf][3][dst1]);                 \
        GLL(TH + wbase + ko,          &lds[buf][4][dst0]);                 \
        GLL(TH + wbase + rstep8 + ko, &lds[buf][4][dst1]);                 \
    } while (0)

    // ---- fragment read offsets. Logical chunk for K-half kc, lane group g
    // (g = lane>>4) is 4*kc + g; physical slot = chunk ^ (row&7).
    // Bank check (8-lane groups): lanes l..l+7 have rows r..r+7 -> slots
    // c^0..c^7 all distinct -> 32 banks covered -> conflict-free.
    const int g = lane >> 4;
    int a_off[4][2], b_off[2][2];
#pragma unroll
    for (int mi = 0; mi < 4; ++mi) {
        int r = wm * 64 + mi * 16 + (lane & 15);
#pragma unroll
        for (int kc = 0; kc < 2; ++kc)
            a_off[mi][kc] = r * BK + ((kc * 4 + g) ^ (r & 7)) * 8;
    }
#pragma unroll
    for (int nj = 0; nj < 2; ++nj) {
        int r = wn * 32 + nj * 16 + (lane & 15);
#pragma unroll
        for (int kc = 0; kc < 2; ++kc)
            b_off[nj][kc] = r * BK + ((kc * 4 + g) ^ (r & 7)) * 8;
    }

    const f32x4 zeroc = (f32x4)0.0f;
    f32x4 lin[4][2], num[4][2], den[4][2], win[4][2];
#pragma unroll
    for (int mi = 0; mi < 4; ++mi)
#pragma unroll
        for (int nj = 0; nj < 2; ++nj) {
            lin[mi][nj] = zeroc; num[mi][nj] = zeroc; den[mi][nj] = zeroc;
        }

    // One K-step = one window: 2 K-halves of MFMA, then inline EPILOG on the
    // completed win (3 VALU/elem; exp2(|d|) with log2e pre-folded into T).
#define COMP_EPI(buf) do {                                                 \
        _Pragma("unroll")                                                  \
        for (int kc = 0; kc < 2; ++kc) {                                   \
            short8 bwh[2], bwl[2], bth[2];                                 \
            _Pragma("unroll")                                              \
            for (int nj = 0; nj < 2; ++nj) {                               \
                bwh[nj] = *(const short8*)&lds[buf][2][b_off[nj][kc]];     \
                bwl[nj] = *(const short8*)&lds[buf][3][b_off[nj][kc]];     \
                bth[nj] = *(const short8*)&lds[buf][4][b_off[nj][kc]];     \
            }                                                              \
            _Pragma("unroll")                                              \
            for (int mi = 0; mi < 4; ++mi) {                               \
                short8 ah = *(const short8*)&lds[buf][0][a_off[mi][kc]];   \
                short8 al = *(const short8*)&lds[buf][1][a_off[mi][kc]];   \
                _Pragma("unroll")                                          \
                for (int nj = 0; nj < 2; ++nj) {                           \
                    lin[mi][nj] = MFMA16(ah, bwh[nj], lin[mi][nj]);        \
                    lin[mi][nj] = MFMA16(al, bwh[nj], lin[mi][nj]);        \
                    lin[mi][nj] = MFMA16(ah, bwl[nj], lin[mi][nj]);        \
                    win[mi][nj] = MFMA16(ah, bth[nj],                      \
                                         (kc == 0) ? zeroc : win[mi][nj]); \
                }                                                          \
            }                                                              \
        }                                                                  \
        _Pragma("unroll")                                                  \
        for (int mi = 0; mi < 4; ++mi)                                     \
        _Pragma("unroll")                                                  \
        for (int nj = 0; nj < 2; ++nj)                                     \
        _Pragma("unroll")                                                  \
        for (int i = 0; i < 4; ++i) {                                      \
            float d = win[mi][nj][i];                                      \
            float e = exp2f(fabsf(d));                                     \
            den[mi][nj][i] += e;                                           \
            num[mi][nj][i] = fmaf(e, d, num[mi][nj][i]);                   \
        }                                                                  \
    } while (0)

    STAGE(0, 0);
    __syncthreads();

    // One barrier per K=64 step. The barrier's vmcnt drain waits on GLLs
    // issued a full step (~3500 cy) earlier -> latency covered. WAR on the
    // re-staged buffer is separated by that same barrier.
#pragma unroll 1
    for (int w = 0; w < 16; ++w) {
        const int t0 = 2 * w;
        STAGE(1, t0 + 1);
        COMP_EPI(0);
        __syncthreads();
        if (t0 + 2 < 32) STAGE(0, t0 + 2);
        COMP_EPI(1);
        __syncthreads();
    }

    // Final epilogue: g = (num/den)*ln2, silu, multiply, store.
#pragma unroll
    for (int mi = 0; mi < 4; ++mi)
#pragma unroll
        for (int nj = 0; nj < 2; ++nj)
#pragma unroll
            for (int i = 0; i < 4; ++i) {
                float gg   = (num[mi][nj][i] / den[mi][nj][i]) * LN2;
                float gate = gg / (1.0f + __expf(-gg));
                float val  = gate * lin[mi][nj][i];
                int r = row0 + wm * 64 + mi * 16 + (lane >> 4) * 4 + i;
                int c = col0 + wn * 32 + nj * 16 + (lane & 15);
                O[(size_t)r * H_DIM + c] = val;
            }
#undef STAGE
#undef COMP_EPI
}

// ------------------------------------------------- fallback (round-1 path) --
__global__ __launch_bounds__(512) void dend_fused_v0(
    const float* __restrict__ X, const float* __restrict__ T,
    const float* __restrict__ W, float* __restrict__ O)
{
    __shared__ __align__(16) short lds[2][5][128 * 32];

    const int tid  = threadIdx.x;
    const int lane = tid & 63;
    const int wv   = tid >> 6;
    const int wm   = wv >> 2;
    const int wn   = wv & 3;

    const int bid     = blockIdx.x;
    const int logical = (bid & 7) * 32 + (bid >> 3);
    const int hb   = logical >> 5;
    const int nb   = logical & 31;
    const int row0 = nb * 128;
    const int col0 = hb * 128;

    const int srow  = tid >> 2;
    const int schn  = tid & 3;
    const int sslot = schn ^ ((srow >> 1) & 3);
    const int swoff = srow * 32 + sslot * 8;

    const float* gx = X + (size_t)(row0 + srow) * K_DIM + schn * 8;
    const float* gw = W + (size_t)(col0 + srow) * K_DIM + schn * 8;
    const float* gt = T + (size_t)(col0 + srow) * K_DIM + schn * 8;

    const int g = lane >> 4;
    int a_off[4], b_off[2];
#pragma unroll
    for (int mi = 0; mi < 4; ++mi) {
        int r = wm * 64 + mi * 16 + (lane & 15);
        a_off[mi] = r * 32 + (g ^ ((r >> 1) & 3)) * 8;
    }
#pragma unroll
    for (int nj = 0; nj < 2; ++nj) {
        int r = wn * 32 + nj * 16 + (lane & 15);
        b_off[nj] = r * 32 + (g ^ ((r >> 1) & 3)) * 8;
    }

    const f32x4 zeroc = (f32x4)0.0f;
    f32x4 lin[4][2], num[4][2], den[4][2], win[4][2];
#pragma unroll
    for (int mi = 0; mi < 4; ++mi)
#pragma unroll
        for (int nj = 0; nj < 2; ++nj) {
            lin[mi][nj] = zeroc; num[mi][nj] = zeroc; den[mi][nj] = zeroc;
        }

    f32x4 rx0, rx1, rw0, rw1, rt0, rt1;

#define LOADS(t) do {                                                   \
        const float* px = gx + (size_t)(t) * 32;                        \
        const float* pw = gw + (size_t)(t) * 32;                        \
        const float* pt = gt + (size_t)(t) * 32;                        \
        rx0 = *(const f32x4*)(px); rx1 = *(const f32x4*)(px + 4);       \
        rw0 = *(const f32x4*)(pw); rw1 = *(const f32x4*)(pw + 4);       \
        rt0 = *(const f32x4*)(pt); rt1 = *(const f32x4*)(pt + 4);       \
    } while (0)

#define WRITE(buf) do {                                                 \
        short8 vh, vl;                                                  \
        cvt_split(rx0, rx1, vh, vl);                                    \
        *(short8*)&lds[buf][0][swoff] = vh;                             \
        *(short8*)&lds[buf][1][swoff] = vl;                             \
        cvt_split(rw0, rw1, vh, vl);                                    \
        *(short8*)&lds[buf][2][swoff] = vh;                             \
        *(short8*)&lds[buf][3][swoff] = vl;                             \
        *(short8*)&lds[buf][4][swoff] = cvt_hi(rt0, rt1);               \
    } while (0)

#define COMPUTE(buf, ZW) do {                                           \
        short8 bwh[2], bwl[2], bth[2];                                  \
        _Pragma("unroll")                                               \
        for (int nj = 0; nj < 2; ++nj) {                                \
            bwh[nj] = *(const short8*)&lds[buf][2][b_off[nj]];          \
            bwl[nj] = *(const short8*)&lds[buf][3][b_off[nj]];          \
            bth[nj] = *(const short8*)&lds[buf][4][b_off[nj]];          \
        }                                                               \
        _Pragma("unroll")                                               \
        for (int mi = 0; mi < 4; ++mi) {                                \
            short8 ah = *(const short8*)&lds[buf][0][a_off[mi]];        \
            short8 al = *(const short8*)&lds[buf][1][a_off[mi]];        \
            _Pragma("unroll")                                           \
            for (int nj = 0; nj < 2; ++nj) {                            \
                lin[mi][nj] = MFMA16(ah, bwh[nj], lin[mi][nj]);         \
                lin[mi][nj] = MFMA16(al, bwh[nj], lin[mi][nj]);         \
                lin[mi][nj] = MFMA16(ah, bwl[nj], lin[mi][nj]);         \
                win[mi][nj] = MFMA16(ah, bth[nj], (ZW) ? zeroc : win[mi][nj]); \
            }                                                           \
        }                                                               \
    } while (0)

#define EPILOG() do {                                                   \
        _Pragma("unroll")                                               \
        for (int mi = 0; mi < 4; ++mi)                                  \
        _Pragma("unroll")                                               \
        for (int nj = 0; nj < 2; ++nj)                                  \
        _Pragma("unroll")                                               \
        for (int i = 0; i < 4; ++i) {                                   \
            float d = win[mi][nj][i];                                   \
            float e = __expf(fabsf(d));                                 \
            den[mi][nj][i] += e;                                        \
            num[mi][nj][i] = fmaf(e, d, num[mi][nj][i]);                \
        }                                                               \
    } while (0)

    LOADS(0);
    WRITE(0);
    __syncthreads();

#pragma unroll 1
    for (int w = 0; w < 32; ++w) {
        const int t0 = 2 * w;
        LOADS(t0 + 1);
        COMPUTE(0, true);
        __syncthreads();
        WRITE(1);
        __syncthreads();
        const bool more = (w < 31);
        if (more) LOADS(t0 + 2);
        COMPUTE(1, false);
        EPILOG();
        __syncthreads();
        if (more) WRITE(0);
        __syncthreads();
    }

#pragma unroll
    for (int mi = 0; mi < 4; ++mi)
#pragma unroll
        for (int nj = 0; nj < 2; ++nj)
#pragma unroll
            for (int i = 0; i < 4; ++i) {
                float gg   = num[mi][nj][i] / den[mi][nj][i];
                float gate = gg / (1.0f + __expf(-gg));
                float val  = gate * lin[mi][nj][i];
                int r = row0 + wm * 64 + mi * 16 + (lane >> 4) * 4 + i;
                int c = col0 + wn * 32 + nj * 16 + (lane & 15);
                O[(size_t)r * H_DIM + c] = val;
            }
#undef LOADS
#undef WRITE
#undef COMPUTE
#undef EPILOG
}

extern "C" void kernel_launch(void* const* d_in, const int* in_sizes, int n_in,
                              void* d_out, int out_size, void* d_ws, size_t ws_size,
                              hipStream_t stream) {
    const float* X = (const float*)d_in[0];   // x [4096,2048]
    const float* T = (const float*)d_in[1];   // template_flat [1024,2048]
    const float* W = (const float*)d_in[2];   // weights [1024,2048]
    float* O = (float*)d_out;                 // [4096,1024]
    (void)in_sizes; (void)n_in; (void)out_size;

    if (ws_size >= WS_NEED) {
        unsigned short* XHp = (unsigned short*)d_ws;
        unsigned short* XLp = XHp + X_ELEMS;
        unsigned short* WHp = XLp + X_ELEMS;
        unsigned short* WLp = WHp + W_ELEMS;
        unsigned short* THp = WLp + W_ELEMS;
        prepass_all<<<XB + 2 * WB, 256, 0, stream>>>(X, W, T, XHp, XLp, WHp, WLp, THp);
        dend_gemm<<<256, 512, 0, stream>>>(XHp, XLp, WHp, WLp, THp, O);
    } else {
        dend_fused_v0<<<256, 512, 0, stream>>>(X, T, W, O);
    }
}

// Round 10
// 91.687 us; speedup vs baseline: 2.3231x; 1.1695x over previous
//
#include <hip/hip_runtime.h>
#include <hip/hip_bf16.h>

// DendriticLayerSiLU: out = silu(softmax-gated template proj) * (x @ W^T)
// N=4096 tokens, K=2048, H=1024, 32 windows of 64.
// Round 10: r9 (BK=64, window==K-step, 160 KB dbuf, chunk^(row&7) swizzle,
// one barrier per K=64) + raw v_exp_f32 for the gate exp (exp2f was
// lowering to the ~8-instr ocml lib routine -> VALUBusy 42%) + T5 setprio
// around the MFMA clusters (role-split waves exist due to inline EPILOG).

typedef __attribute__((ext_vector_type(8))) short short8;
typedef __attribute__((ext_vector_type(4))) float f32x4;

#define N_TOK 4096
#define K_DIM 2048
#define H_DIM 1024
#define BM 128
#define BH 128
#define BK 64
#define LDSZ (BM * BK)            // 8192 shorts = 16 KB per array

#define X_ELEMS (N_TOK * K_DIM)   // 8388608
#define W_ELEMS (H_DIM * K_DIM)   // 2097152
#define WS_NEED ((size_t)(2 * X_ELEMS + 3 * W_ELEMS) * 2)  // 46,137,344 B

#define XB (X_ELEMS / 8 / 256)    // 4096 prepass blocks for X
#define WB (W_ELEMS / 8 / 256)    // 1024 for W, 1024 for T

#define LOG2E 1.4426950408889634f
#define LN2   0.6931471805599453f

// raw v_exp_f32 (computes 2^x, ~1 ULP) — same HW instr __expf uses.
#if defined(__has_builtin)
#if __has_builtin(__builtin_amdgcn_exp2f)
#define EXP2RAW(x) __builtin_amdgcn_exp2f(x)
#endif
#endif
#ifndef EXP2RAW
__device__ __forceinline__ float exp2raw_asm(float x) {
    float r;
    asm("v_exp_f32 %0, %1" : "=v"(r) : "v"(x));
    return r;
}
#define EXP2RAW(x) exp2raw_asm(x)
#endif

__device__ __forceinline__ unsigned short f2bf(float f) {
    unsigned int u = __float_as_uint(f);
    u += 0x7FFFu + ((u >> 16) & 1u);    // round-to-nearest-even
    return (unsigned short)(u >> 16);
}
__device__ __forceinline__ float bf2f(unsigned short h) {
    return __uint_as_float(((unsigned int)h) << 16);
}

__device__ __forceinline__ void cvt_split(f32x4 a, f32x4 b, short8& vh, short8& vl) {
#pragma unroll
    for (int i = 0; i < 4; ++i) {
        float f = a[i];
        unsigned short h = f2bf(f);
        vh[i] = (short)h;
        vl[i] = (short)f2bf(f - bf2f(h));
    }
#pragma unroll
    for (int i = 0; i < 4; ++i) {
        float f = b[i];
        unsigned short h = f2bf(f);
        vh[i + 4] = (short)h;
        vl[i + 4] = (short)f2bf(f - bf2f(h));
    }
}
__device__ __forceinline__ short8 cvt_hi(f32x4 a, f32x4 b) {
    short8 v;
#pragma unroll
    for (int i = 0; i < 4; ++i) { v[i] = (short)f2bf(a[i]); v[i + 4] = (short)f2bf(b[i]); }
    return v;
}

#define MFMA16(A, B, C) __builtin_amdgcn_mfma_f32_16x16x32_bf16(A, B, C, 0, 0, 0)

// ---------------------------------------------------------------- prepass ---
// X,W -> hi/lo bf16 split; T -> bf16 scaled by log2e (exp2-based softmax).
__global__ __launch_bounds__(256) void prepass_all(
    const float* __restrict__ X, const float* __restrict__ W,
    const float* __restrict__ T,
    unsigned short* __restrict__ XH, unsigned short* __restrict__ XL,
    unsigned short* __restrict__ WH, unsigned short* __restrict__ WL,
    unsigned short* __restrict__ TH)
{
    int b = blockIdx.x;
    if (b < XB + WB) {
        const float* src; unsigned short *hi, *lo; int i;
        if (b < XB) { src = X; hi = XH; lo = XL; i = b * 256 + threadIdx.x; }
        else        { src = W; hi = WH; lo = WL; i = (b - XB) * 256 + threadIdx.x; }
        const float* p = src + (size_t)i * 8;
        f32x4 a = *(const f32x4*)p;
        f32x4 c = *(const f32x4*)(p + 4);
        short8 vh, vl;
        cvt_split(a, c, vh, vl);
        *(short8*)&hi[(size_t)i * 8] = vh;
        *(short8*)&lo[(size_t)i * 8] = vl;
    } else {
        int i = (b - XB - WB) * 256 + threadIdx.x;
        const float* p = T + (size_t)i * 8;
        f32x4 a = *(const f32x4*)p;
        f32x4 c = *(const f32x4*)(p + 4);
#pragma unroll
        for (int j = 0; j < 4; ++j) { a[j] *= LOG2E; c[j] *= LOG2E; }
        *(short8*)&TH[(size_t)i * 8] = cvt_hi(a, c);
    }
}

// ------------------------------------------------------------- main GEMM ----
#define GLL(gp, lp) __builtin_amdgcn_global_load_lds(                      \
        (const __attribute__((address_space(1))) void*)(gp),               \
        (__attribute__((address_space(3))) void*)(lp), 16, 0, 0)

__global__ __launch_bounds__(512) void dend_gemm(
    const unsigned short* __restrict__ XH, const unsigned short* __restrict__ XL,
    const unsigned short* __restrict__ WH, const unsigned short* __restrict__ WL,
    const unsigned short* __restrict__ TH, float* __restrict__ O)
{
    // arrays: 0=x_hi 1=x_lo 2=w_hi 3=w_lo 4=t_hi ; [128][64] shorts each;
    // double-buffered -> 160 KB (full CU LDS, 1 block/CU by design).
    __shared__ __align__(16) short lds[2][5][LDSZ];

    const int tid  = threadIdx.x;
    const int lane = tid & 63;
    const int wv   = tid >> 6;    // 0..7
    const int wm   = wv >> 2;     // 0..1  (64 token-rows each)
    const int wn   = wv & 3;      // 0..3  (32 units each)

    const int bid     = blockIdx.x;
    const int logical = (bid & 7) * 32 + (bid >> 3);   // XCD-chunked swizzle
    const int hb   = logical >> 5;   // 0..7
    const int nb   = logical & 31;   // 0..31
    const int row0 = nb * BM;
    const int col0 = hb * BH;

    // ---- staging: row = 64 shorts = 8 chunks of 16B. Swizzle:
    //   content(row, slot) = logical chunk  slot ^ (row & 7).
    // GLL (1 KB linear): lane l -> row +(l>>3), slot l&7  =>
    //   source chunk = (l&7) ^ (l>>3).  Two GLLs per 16-row wave stripe.
    const int srow8 = lane >> 3;                 // 0..7
    const int schk  = (lane & 7) ^ srow8;        // pre-swizzled source chunk
    const size_t xbase = (size_t)(row0 + wv * 16 + srow8) * K_DIM + schk * 8;
    const size_t wbase = (size_t)(col0 + wv * 16 + srow8) * K_DIM + schk * 8;
    const size_t rstep8 = (size_t)8 * K_DIM;     // +8 rows
    const int dst0 = (wv * 16) * BK;             // short index of stripe row 0
    const int dst1 = dst0 + 8 * BK;

#define STAGE(buf, t) do {                                                 \
        const size_t ko = (size_t)(t) * BK;                                \
        GLL(XH + xbase + ko,          &lds[buf][0][dst0]);                 \
        GLL(XH + xbase + rstep8 + ko, &lds[buf][0][dst1]);                 \
        GLL(XL + xbase + ko,          &lds[buf][1][dst0]);                 \
        GLL(XL + xbase + rstep8 + ko, &lds[buf][1][dst1]);                 \
        GLL(WH + wbase + ko,          &lds[buf][2][dst0]);                 \
        GLL(WH + wbase + rstep8 + ko, &lds[buf][2][dst1]);                 \
        GLL(WL + wbase + ko,          &lds[buf][3][dst0]);                 \
        GLL(WL + wbase + rstep8 + ko, &lds[buf][3][dst1]);                 \
        GLL(TH + wbase + ko,          &lds[buf][4][dst0]);                 \
        GLL(TH + wbase + rstep8 + ko, &lds[buf][4][dst1]);                 \
    } while (0)

    // ---- fragment read offsets. Logical chunk for K-half kc, lane group g
    // (g = lane>>4) is 4*kc + g; physical slot = chunk ^ (row&7).
    // Bank check (8-lane groups): lanes l..l+7 have rows r..r+7 -> slots
    // c^0..c^7 all distinct -> 32 banks covered -> conflict-free (measured 0).
    const int g = lane >> 4;
    int a_off[4][2], b_off[2][2];
#pragma unroll
    for (int mi = 0; mi < 4; ++mi) {
        int r = wm * 64 + mi * 16 + (lane & 15);
#pragma unroll
        for (int kc = 0; kc < 2; ++kc)
            a_off[mi][kc] = r * BK + ((kc * 4 + g) ^ (r & 7)) * 8;
    }
#pragma unroll
    for (int nj = 0; nj < 2; ++nj) {
        int r = wn * 32 + nj * 16 + (lane & 15);
#pragma unroll
        for (int kc = 0; kc < 2; ++kc)
            b_off[nj][kc] = r * BK + ((kc * 4 + g) ^ (r & 7)) * 8;
    }

    const f32x4 zeroc = (f32x4)0.0f;
    f32x4 lin[4][2], num[4][2], den[4][2], win[4][2];
#pragma unroll
    for (int mi = 0; mi < 4; ++mi)
#pragma unroll
        for (int nj = 0; nj < 2; ++nj) {
            lin[mi][nj] = zeroc; num[mi][nj] = zeroc; den[mi][nj] = zeroc;
        }

    // One K-step = one window: 2 K-halves of MFMA (setprio-wrapped), then
    // inline EPILOG on the completed win. e = v_exp_f32(|d|) = exp(|a|)
    // since T carries log2e from the prepass. 3 VALU/elem true cost.
#define COMP_EPI(buf) do {                                                 \
        _Pragma("unroll")                                                  \
        for (int kc = 0; kc < 2; ++kc) {                                   \
            short8 bwh[2], bwl[2], bth[2];                                 \
            _Pragma("unroll")                                              \
            for (int nj = 0; nj < 2; ++nj) {                               \
                bwh[nj] = *(const short8*)&lds[buf][2][b_off[nj][kc]];     \
                bwl[nj] = *(const short8*)&lds[buf][3][b_off[nj][kc]];     \
                bth[nj] = *(const short8*)&lds[buf][4][b_off[nj][kc]];     \
            }                                                              \
            __builtin_amdgcn_s_setprio(1);                                 \
            _Pragma("unroll")                                              \
            for (int mi = 0; mi < 4; ++mi) {                               \
                short8 ah = *(const short8*)&lds[buf][0][a_off[mi][kc]];   \
                short8 al = *(const short8*)&lds[buf][1][a_off[mi][kc]];   \
                _Pragma("unroll")                                          \
                for (int nj = 0; nj < 2; ++nj) {                           \
                    lin[mi][nj] = MFMA16(ah, bwh[nj], lin[mi][nj]);        \
                    lin[mi][nj] = MFMA16(al, bwh[nj], lin[mi][nj]);        \
                    lin[mi][nj] = MFMA16(ah, bwl[nj], lin[mi][nj]);        \
                    win[mi][nj] = MFMA16(ah, bth[nj],                      \
                                         (kc == 0) ? zeroc : win[mi][nj]); \
                }                                                          \
            }                                                              \
            __builtin_amdgcn_s_setprio(0);                                 \
        }                                                                  \
        _Pragma("unroll")                                                  \
        for (int mi = 0; mi < 4; ++mi)                                     \
        _Pragma("unroll")                                                  \
        for (int nj = 0; nj < 2; ++nj)                                     \
        _Pragma("unroll")                                                  \
        for (int i = 0; i < 4; ++i) {                                      \
            float d = win[mi][nj][i];                                      \
            float e = EXP2RAW(fabsf(d));                                   \
            den[mi][nj][i] += e;                                           \
            num[mi][nj][i] = fmaf(e, d, num[mi][nj][i]);                   \
        }                                                                  \
    } while (0)

    STAGE(0, 0);
    __syncthreads();

    // One barrier per K=64 step. The barrier's vmcnt drain waits on GLLs
    // issued a ~half-step (~3500 cy) earlier -> latency covered. WAR on the
    // re-staged buffer is separated by that same barrier.
#pragma unroll 1
    for (int w = 0; w < 16; ++w) {
        const int t0 = 2 * w;
        STAGE(1, t0 + 1);
        COMP_EPI(0);
        __syncthreads();
        if (t0 + 2 < 32) STAGE(0, t0 + 2);
        COMP_EPI(1);
        __syncthreads();
    }

    // Final epilogue: g = (num/den)*ln2, silu, multiply, store.
#pragma unroll
    for (int mi = 0; mi < 4; ++mi)
#pragma unroll
        for (int nj = 0; nj < 2; ++nj)
#pragma unroll
            for (int i = 0; i < 4; ++i) {
                float gg   = (num[mi][nj][i] / den[mi][nj][i]) * LN2;
                float gate = gg / (1.0f + __expf(-gg));
                float val  = gate * lin[mi][nj][i];
                int r = row0 + wm * 64 + mi * 16 + (lane >> 4) * 4 + i;
                int c = col0 + wn * 32 + nj * 16 + (lane & 15);
                O[(size_t)r * H_DIM + c] = val;
            }
#undef STAGE
#undef COMP_EPI
}

// ------------------------------------------------- fallback (round-1 path) --
__global__ __launch_bounds__(512) void dend_fused_v0(
    const float* __restrict__ X, const float* __restrict__ T,
    const float* __restrict__ W, float* __restrict__ O)
{
    __shared__ __align__(16) short lds[2][5][128 * 32];

    const int tid  = threadIdx.x;
    const int lane = tid & 63;
    const int wv   = tid >> 6;
    const int wm   = wv >> 2;
    const int wn   = wv & 3;

    const int bid     = blockIdx.x;
    const int logical = (bid & 7) * 32 + (bid >> 3);
    const int hb   = logical >> 5;
    const int nb   = logical & 31;
    const int row0 = nb * 128;
    const int col0 = hb * 128;

    const int srow  = tid >> 2;
    const int schn  = tid & 3;
    const int sslot = schn ^ ((srow >> 1) & 3);
    const int swoff = srow * 32 + sslot * 8;

    const float* gx = X + (size_t)(row0 + srow) * K_DIM + schn * 8;
    const float* gw = W + (size_t)(col0 + srow) * K_DIM + schn * 8;
    const float* gt = T + (size_t)(col0 + srow) * K_DIM + schn * 8;

    const int g = lane >> 4;
    int a_off[4], b_off[2];
#pragma unroll
    for (int mi = 0; mi < 4; ++mi) {
        int r = wm * 64 + mi * 16 + (lane & 15);
        a_off[mi] = r * 32 + (g ^ ((r >> 1) & 3)) * 8;
    }
#pragma unroll
    for (int nj = 0; nj < 2; ++nj) {
        int r = wn * 32 + nj * 16 + (lane & 15);
        b_off[nj] = r * 32 + (g ^ ((r >> 1) & 3)) * 8;
    }

    const f32x4 zeroc = (f32x4)0.0f;
    f32x4 lin[4][2], num[4][2], den[4][2], win[4][2];
#pragma unroll
    for (int mi = 0; mi < 4; ++mi)
#pragma unroll
        for (int nj = 0; nj < 2; ++nj) {
            lin[mi][nj] = zeroc; num[mi][nj] = zeroc; den[mi][nj] = zeroc;
        }

    f32x4 rx0, rx1, rw0, rw1, rt0, rt1;

#define LOADS(t) do {                                                   \
        const float* px = gx + (size_t)(t) * 32;                        \
        const float* pw = gw + (size_t)(t) * 32;                        \
        const float* pt = gt + (size_t)(t) * 32;                        \
        rx0 = *(const f32x4*)(px); rx1 = *(const f32x4*)(px + 4);       \
        rw0 = *(const f32x4*)(pw); rw1 = *(const f32x4*)(pw + 4);       \
        rt0 = *(const f32x4*)(pt); rt1 = *(const f32x4*)(pt + 4);       \
    } while (0)

#define WRITE(buf) do {                                                 \
        short8 vh, vl;                                                  \
        cvt_split(rx0, rx1, vh, vl);                                    \
        *(short8*)&lds[buf][0][swoff] = vh;                             \
        *(short8*)&lds[buf][1][swoff] = vl;                             \
        cvt_split(rw0, rw1, vh, vl);                                    \
        *(short8*)&lds[buf][2][swoff] = vh;                             \
        *(short8*)&lds[buf][3][swoff] = vl;                             \
        *(short8*)&lds[buf][4][swoff] = cvt_hi(rt0, rt1);               \
    } while (0)

#define COMPUTE(buf, ZW) do {                                           \
        short8 bwh[2], bwl[2], bth[2];                                  \
        _Pragma("unroll")                                               \
        for (int nj = 0; nj < 2; ++nj) {                                \
            bwh[nj] = *(const short8*)&lds[buf][2][b_off[nj]];          \
            bwl[nj] = *(const short8*)&lds[buf][3][b_off[nj]];          \
            bth[nj] = *(const short8*)&lds[buf][4][b_off[nj]];          \
        }                                                               \
        _Pragma("unroll")                                               \
        for (int mi = 0; mi < 4; ++mi) {                                \
            short8 ah = *(const short8*)&lds[buf][0][a_off[mi]];        \
            short8 al = *(const short8*)&lds[buf][1][a_off[mi]];        \
            _Pragma("unroll")                                           \
            for (int nj = 0; nj < 2; ++nj) {                            \
                lin[mi][nj] = MFMA16(ah, bwh[nj], lin[mi][nj]);         \
                lin[mi][nj] = MFMA16(al, bwh[nj], lin[mi][nj]);         \
                lin[mi][nj] = MFMA16(ah, bwl[nj], lin[mi][nj]);         \
                win[mi][nj] = MFMA16(ah, bth[nj], (ZW) ? zeroc : win[mi][nj]); \
            }                                                           \
        }                                                               \
    } while (0)

#define EPILOG() do {                                                   \
        _Pragma("unroll")                                               \
        for (int mi = 0; mi < 4; ++mi)                                  \
        _Pragma("unroll")                                               \
        for (int nj = 0; nj < 2; ++nj)                                  \
        _Pragma("unroll")                                               \
        for (int i = 0; i < 4; ++i) {                                   \
            float d = win[mi][nj][i];                                   \
            float e = __expf(fabsf(d));                                 \
            den[mi][nj][i] += e;                                        \
            num[mi][nj][i] = fmaf(e, d, num[mi][nj][i]);                \
        }                                                               \
    } while (0)

    LOADS(0);
    WRITE(0);
    __syncthreads();

#pragma unroll 1
    for (int w = 0; w < 32; ++w) {
        const int t0 = 2 * w;
        LOADS(t0 + 1);
        COMPUTE(0, true);
        __syncthreads();
        WRITE(1);
        __syncthreads();
        const bool more = (w < 31);
        if (more) LOADS(t0 + 2);
        COMPUTE(1, false);
        EPILOG();
        __syncthreads();
        if (more) WRITE(0);
        __syncthreads();
    }

#pragma unroll
    for (int mi = 0; mi < 4; ++mi)
#pragma unroll
        for (int nj = 0; nj < 2; ++nj)
#pragma unroll
            for (int i = 0; i < 4; ++i) {
                float gg   = num[mi][nj][i] / den[mi][nj][i];
                float gate = gg / (1.0f + __expf(-gg));
                float val  = gate * lin[mi][nj][i];
                int r = row0 + wm * 64 + mi * 16 + (lane >> 4) * 4 + i;
                int c = col0 + wn * 32 + nj * 16 + (lane & 15);
                O[(size_t)r * H_DIM + c] = val;
            }
#undef LOADS
#undef WRITE
#undef COMPUTE
#undef EPILOG
}

extern "C" void kernel_launch(void* const* d_in, const int* in_sizes, int n_in,
                              void* d_out, int out_size, void* d_ws, size_t ws_size,
                              hipStream_t stream) {
    const float* X = (const float*)d_in[0];   // x [4096,2048]
    const float* T = (const float*)d_in[1];   // template_flat [1024,2048]
    const float* W = (const float*)d_in[2];   // weights [1024,2048]
    float* O = (float*)d_out;                 // [4096,1024]
    (void)in_sizes; (void)n_in; (void)out_size;

    if (ws_size >= WS_NEED) {
        unsigned short* XHp = (unsigned short*)d_ws;
        unsigned short* XLp = XHp + X_ELEMS;
        unsigned short* WHp = XLp + X_ELEMS;
        unsigned short* WLp = WHp + W_ELEMS;
        unsigned short* THp = WLp + W_ELEMS;
        prepass_all<<<XB + 2 * WB, 256, 0, stream>>>(X, W, T, XHp, XLp, WHp, WLp, THp);
        dend_gemm<<<256, 512, 0, stream>>>(XHp, XLp, WHp, WLp, THp, O);
    } else {
        dend_fused_v0<<<256, 512, 0, stream>>>(X, T, W, O);
    }
}